// Round 1
// baseline (494.528 us; speedup 1.0000x reference)
//
#include <hip/hip_runtime.h>
#include <hip/hip_bf16.h>

#define NB 8
#define BIN 512
#define BOUT 512
#define BATCH 16384
#define NCOL (NB * BIN) /* 4096 */

typedef __bf16 bf16x8 __attribute__((ext_vector_type(8)));
typedef float floatx4 __attribute__((ext_vector_type(4)));

// async global->LDS, 16B per lane; LDS dest is wave-uniform base + lane*16
#define GLDS16(gptr, lptr)                                                 \
    __builtin_amdgcn_global_load_lds(                                      \
        (const __attribute__((address_space(1))) void*)(gptr),             \
        (__attribute__((address_space(3))) void*)(lptr), 16, 0, 0)

// ---------------------------------------------------------------------------
// Prep: W [g][o][i] fp32  ->  ws bf16, fragment-major 16B chunks:
//   chunk c = ((g*32 + n16)*16 + k32)*64 + lane
//   element j of chunk = W[g][n16*16 + (lane&15)][k32*32 + (lane>>4)*8 + j]
// This makes GEMM B-staging a linear copy and B ds_read_b128 lane-contiguous.
// ---------------------------------------------------------------------------
__global__ __launch_bounds__(256) void convW_kernel(const float* __restrict__ W,
                                                    __bf16* __restrict__ wsB) {
    int c = blockIdx.x * 256 + threadIdx.x;  // 0 .. 262143
    int lane = c & 63;
    int k32  = (c >> 6) & 15;
    int n16  = (c >> 10) & 31;
    int g    = c >> 15;
    int n = n16 * 16 + (lane & 15);
    int k = k32 * 32 + ((lane >> 4) << 3);
    const float* src = W + ((size_t)g * BOUT + n) * BIN + k;
    float4 f0 = *(const float4*)src;
    float4 f1 = *(const float4*)(src + 4);
    bf16x8 v;
    v[0] = (__bf16)f0.x; v[1] = (__bf16)f0.y; v[2] = (__bf16)f0.z; v[3] = (__bf16)f0.w;
    v[4] = (__bf16)f1.x; v[5] = (__bf16)f1.y; v[6] = (__bf16)f1.z; v[7] = (__bf16)f1.w;
    *(bf16x8*)(wsB + (size_t)c * 8) = v;
}

// ---------------------------------------------------------------------------
// GEMM: per block one 128x128 output tile of one group.
// BM=128, BN=128, BK=64; 256 threads = 4 waves; wave -> 64x64 (4x4 MFMA tiles).
// LDS layout (both A and B): fragment-major chunks
//   chunk = ((t16*2 + k32)*64 + lane), 16B each; t16 = m16 or n16 local index.
// ---------------------------------------------------------------------------
__global__ __launch_bounds__(256, 2) void bgemm_kernel(
        const float* __restrict__ x, const __bf16* __restrict__ wsB,
        const float* __restrict__ bias, float* __restrict__ out) {
    __shared__ __align__(16) __bf16 Ash[128 * 64];
    __shared__ __align__(16) __bf16 Bsh[128 * 64];

    // XCD swizzle: blocks b, b+8, b+16... land on the same XCD (round-robin
    // dispatch heuristic). t = (b>>3) + 512*(b&7) with n-tile innermost =>
    // each XCD owns one group g; 4 n-tiles of an m-tile run adjacently -> L2
    // reuse of the 256KB x tile; W slice (512KB bf16) L2-resident.
    int b = blockIdx.x;
    int t = (b >> 3) + ((b & 7) << 9);
    int g  = t >> 9;          // 0..7
    int mt = (t >> 2) & 127;  // 0..127
    int nt = t & 3;           // 0..3

    int tid  = threadIdx.x;
    int lane = tid & 63;
    int wave = tid >> 6;
    int wm = wave >> 1, wn = wave & 1;
    int m0 = mt * 128;

    // A staging precompute: per i, this thread loads 8 consecutive floats of
    // one x row (coalesced), converts, writes one 16B fragment-major chunk.
    const float* axp[4];
    int achunk[4];
#pragma unroll
    for (int i = 0; i < 4; ++i) {
        int hr  = i * 256 + tid;
        int row = hr >> 3;  // 0..127
        int s   = hr & 7;   // 8-float chunk within BK=64
        axp[i]    = x + (size_t)(m0 + row) * NCOL + g * BIN + s * 8;
        achunk[i] = ((row >> 4) * 2 + (s >> 2)) * 64 + (s & 3) * 16 + (row & 15);
    }
    // B staging precompute (linear async copy from pre-swizzled ws)
    size_t   bgoff[4];
    unsigned bldsoff[4];
#pragma unroll
    for (int i = 0; i < 4; ++i) {
        int c    = i * 256 + tid;
        int n16l = c >> 7;
        int k32l = (c >> 6) & 1;
        int lan  = c & 63;
        bgoff[i]   = ((size_t)(((g * 32 + nt * 8 + n16l) * 16) + k32l) * 64 + lan) * 8;
        bldsoff[i] = (unsigned)(i * 256 + wave * 64) * 8;  // wave-uniform
    }

    floatx4 acc[4][4];
#pragma unroll
    for (int i = 0; i < 4; ++i)
#pragma unroll
        for (int j = 0; j < 4; ++j) {
            floatx4 z = {0.f, 0.f, 0.f, 0.f};
            acc[i][j] = z;
        }

    for (int kb = 0; kb < 8; ++kb) {
        // B: async global->LDS (bf16, already fragment-major in ws)
#pragma unroll
        for (int i = 0; i < 4; ++i)
            GLDS16(wsB + bgoff[i] + (size_t)kb * 1024, Bsh + bldsoff[i]);
        // A: fp32 load + convert + LDS write (fragment-major)
#pragma unroll
        for (int i = 0; i < 4; ++i) {
            const float* p = axp[i] + kb * 64;
            float4 f0 = *(const float4*)p;
            float4 f1 = *(const float4*)(p + 4);
            bf16x8 v;
            v[0] = (__bf16)f0.x; v[1] = (__bf16)f0.y; v[2] = (__bf16)f0.z; v[3] = (__bf16)f0.w;
            v[4] = (__bf16)f1.x; v[5] = (__bf16)f1.y; v[6] = (__bf16)f1.z; v[7] = (__bf16)f1.w;
            *(bf16x8*)(Ash + achunk[i] * 8) = v;
        }
        __syncthreads();  // drains vmcnt (incl. LDS-DMA) + lgkmcnt
#pragma unroll
        for (int ks = 0; ks < 2; ++ks) {
            bf16x8 af[4], bfr[4];
#pragma unroll
            for (int i = 0; i < 4; ++i)
                af[i] = *(const bf16x8*)(Ash + (((wm * 4 + i) * 2 + ks) * 64 + lane) * 8);
#pragma unroll
            for (int j = 0; j < 4; ++j)
                bfr[j] = *(const bf16x8*)(Bsh + (((wn * 4 + j) * 2 + ks) * 64 + lane) * 8);
#pragma unroll
            for (int i = 0; i < 4; ++i)
#pragma unroll
                for (int j = 0; j < 4; ++j)
                    acc[i][j] = __builtin_amdgcn_mfma_f32_16x16x32_bf16(
                        af[i], bfr[j], acc[i][j], 0, 0, 0);
        }
        __syncthreads();  // before next staging overwrites LDS
    }

    // Epilogue: C/D layout col = lane&15, row = (lane>>4)*4 + reg
    int colbase = nt * 128 + wn * 64;
    int rowq = (lane >> 4) * 4;
    int coll = lane & 15;
#pragma unroll
    for (int j = 0; j < 4; ++j) {
        int col  = colbase + j * 16 + coll;  // 0..511 within group
        float bv = bias[g * BOUT + col];
        size_t ocol = (size_t)g * BOUT + col;
#pragma unroll
        for (int i = 0; i < 4; ++i) {
            int rbase = m0 + wm * 64 + i * 16 + rowq;
#pragma unroll
            for (int r = 0; r < 4; ++r)
                out[(size_t)(rbase + r) * NCOL + ocol] = acc[i][j][r] + bv;
        }
    }
}

extern "C" void kernel_launch(void* const* d_in, const int* in_sizes, int n_in,
                              void* d_out, int out_size, void* d_ws, size_t ws_size,
                              hipStream_t stream) {
    const float* x    = (const float*)d_in[0];
    const float* W    = (const float*)d_in[1];
    const float* bias = (const float*)d_in[2];
    float* out  = (float*)d_out;
    __bf16* wsB = (__bf16*)d_ws;  // 4 MB of scratch for bf16-swizzled W

    // W -> bf16 fragment-major swizzle (runs every call; ws is re-poisoned)
    convW_kernel<<<1024, 256, 0, stream>>>(W, wsB);
    // 8 groups x 128 m-tiles x 4 n-tiles = 4096 blocks
    bgemm_kernel<<<4096, 256, 0, stream>>>(x, wsB, bias, out);
}

// Round 2
// 487.234 us; speedup vs baseline: 1.0150x; 1.0150x over previous
//
#include <hip/hip_runtime.h>
#include <hip/hip_bf16.h>

#define NB 8
#define BIN 512
#define BOUT 512
#define BATCH 16384
#define NCOL (NB * BIN) /* 4096 */

typedef __bf16 bf16x8 __attribute__((ext_vector_type(8)));
typedef float floatx4 __attribute__((ext_vector_type(4)));

// async global->LDS, 16B per lane; LDS dest is wave-uniform base + lane*16
#define GLDS16(gptr, lptr)                                                 \
    __builtin_amdgcn_global_load_lds(                                      \
        (const __attribute__((address_space(1))) void*)(gptr),             \
        (__attribute__((address_space(3))) void*)(lptr), 16, 0, 0)

// ---------------------------------------------------------------------------
// Prep: W [g][o][i] fp32  ->  ws bf16, fragment-major 16B chunks:
//   chunk c = ((g*32 + n16)*16 + k32)*64 + lane
//   element j of chunk = W[g][n16*16 + (lane&15)][k32*32 + (lane>>4)*8 + j]
// GEMM B-staging is then a linear async copy and B ds_read_b128 lane-linear.
// ---------------------------------------------------------------------------
__global__ __launch_bounds__(256) void convW_kernel(const float* __restrict__ W,
                                                    __bf16* __restrict__ wsB) {
    int c = blockIdx.x * 256 + threadIdx.x;  // 0 .. 262143
    int lane = c & 63;
    int k32  = (c >> 6) & 15;
    int n16  = (c >> 10) & 31;
    int g    = c >> 15;
    int n = n16 * 16 + (lane & 15);
    int k = k32 * 32 + ((lane >> 4) << 3);
    const float* src = W + ((size_t)g * BOUT + n) * BIN + k;
    float4 f0 = *(const float4*)src;
    float4 f1 = *(const float4*)(src + 4);
    bf16x8 v;
    v[0] = (__bf16)f0.x; v[1] = (__bf16)f0.y; v[2] = (__bf16)f0.z; v[3] = (__bf16)f0.w;
    v[4] = (__bf16)f1.x; v[5] = (__bf16)f1.y; v[6] = (__bf16)f1.z; v[7] = (__bf16)f1.w;
    *(bf16x8*)(wsB + (size_t)c * 8) = v;
}

// ---------------------------------------------------------------------------
// GEMM: per block one 128x128 output tile of one group.
// BM=128, BN=128, BK=64; 256 threads = 4 waves; wave -> 64x64 (4x4 MFMA tiles).
// B LDS layout: fragment-major chunks, chunk = (n16*2 + k32)*64 + lane (16B).
// A LDS layout: XOR-swizzled row-major chunks:
//   chunk(row, s) = row*8 + (s ^ (row & 7)),  s = 8-elem k-chunk (0..7)
//   -> writes: 8 same-row lanes permute 8 consecutive chunks (conflict-free)
//   -> frag reads: chunk%8 = (ks*4+quad)^(lane&7) spreads all 8 bank groups
// ---------------------------------------------------------------------------
__global__ __launch_bounds__(256, 2) void bgemm_kernel(
        const float* __restrict__ x, const __bf16* __restrict__ wsB,
        const float* __restrict__ bias, float* __restrict__ out) {
    __shared__ __align__(16) __bf16 Ash[128 * 64];
    __shared__ __align__(16) __bf16 Bsh[128 * 64];

    // XCD swizzle: t = (b>>3) + 512*(b&7), n-tile innermost => each XCD owns
    // one group g; adjacent n-tiles reuse the x m-tile via L2.
    int b = blockIdx.x;
    int t = (b >> 3) + ((b & 7) << 9);
    int g  = t >> 9;          // 0..7
    int mt = (t >> 2) & 127;  // 0..127
    int nt = t & 3;           // 0..3

    int tid  = threadIdx.x;
    int lane = tid & 63;
    int wave = tid >> 6;
    int wm = wave >> 1, wn = wave & 1;
    int m0 = mt * 128;

    // A staging precompute: thread loads 8 consecutive floats of one x row
    // (coalesced 32B/lane), converts, writes one swizzled 16B chunk.
    const float* axp[4];
    int achunk[4];
#pragma unroll
    for (int i = 0; i < 4; ++i) {
        int hr  = i * 256 + tid;
        int row = hr >> 3;  // 0..127
        int s   = hr & 7;   // 8-float chunk within BK=64
        axp[i]    = x + (size_t)(m0 + row) * NCOL + g * BIN + s * 8;
        achunk[i] = row * 8 + (s ^ (row & 7));  // XOR swizzle
    }
    // B staging precompute (linear async copy from pre-swizzled ws)
    size_t   bgoff[4];
    unsigned bldsoff[4];
#pragma unroll
    for (int i = 0; i < 4; ++i) {
        int c    = i * 256 + tid;
        int n16l = c >> 7;
        int k32l = (c >> 6) & 1;
        int lan  = c & 63;
        bgoff[i]   = ((size_t)(((g * 32 + nt * 8 + n16l) * 16) + k32l) * 64 + lan) * 8;
        bldsoff[i] = (unsigned)(i * 256 + wave * 64) * 8;  // wave-uniform
    }

    // A fragment read address components (swizzled)
    int a_m_lo = (lane & 15) * 8;   // (m&15)*8 chunks
    int a_quad = lane >> 4;         // k-quad
    int a_xor  = lane & 7;          // m&7 == lane&7

    floatx4 acc[4][4];
#pragma unroll
    for (int i = 0; i < 4; ++i)
#pragma unroll
        for (int j = 0; j < 4; ++j) {
            floatx4 z = {0.f, 0.f, 0.f, 0.f};
            acc[i][j] = z;
        }

    for (int kb = 0; kb < 8; ++kb) {
        // B: async global->LDS (bf16, already fragment-major in ws)
#pragma unroll
        for (int i = 0; i < 4; ++i)
            GLDS16(wsB + bgoff[i] + (size_t)kb * 1024, Bsh + bldsoff[i]);
        // A: fp32 load + convert + LDS write (XOR-swizzled, conflict-free)
#pragma unroll
        for (int i = 0; i < 4; ++i) {
            const float* p = axp[i] + kb * 64;
            float4 f0 = *(const float4*)p;
            float4 f1 = *(const float4*)(p + 4);
            bf16x8 v;
            v[0] = (__bf16)f0.x; v[1] = (__bf16)f0.y; v[2] = (__bf16)f0.z; v[3] = (__bf16)f0.w;
            v[4] = (__bf16)f1.x; v[5] = (__bf16)f1.y; v[6] = (__bf16)f1.z; v[7] = (__bf16)f1.w;
            *(bf16x8*)(Ash + achunk[i] * 8) = v;
        }
        __syncthreads();  // drains vmcnt (incl. LDS-DMA) + lgkmcnt
#pragma unroll
        for (int ks = 0; ks < 2; ++ks) {
            bf16x8 af[4], bfr[4];
#pragma unroll
            for (int i = 0; i < 4; ++i) {
                int chunk = ((wm * 4 + i) * 16) * 8 + a_m_lo +
                            ((ks * 4 + a_quad) ^ a_xor);
                af[i] = *(const bf16x8*)(Ash + chunk * 8);
            }
#pragma unroll
            for (int j = 0; j < 4; ++j)
                bfr[j] = *(const bf16x8*)(Bsh + (((wn * 4 + j) * 2 + ks) * 64 + lane) * 8);
#pragma unroll
            for (int i = 0; i < 4; ++i)
#pragma unroll
                for (int j = 0; j < 4; ++j)
                    acc[i][j] = __builtin_amdgcn_mfma_f32_16x16x32_bf16(
                        af[i], bfr[j], acc[i][j], 0, 0, 0);
        }
        __syncthreads();  // before next staging overwrites LDS
    }

    // Epilogue: C/D layout col = lane&15, row = (lane>>4)*4 + reg
    int colbase = nt * 128 + wn * 64;
    int rowq = (lane >> 4) * 4;
    int coll = lane & 15;
#pragma unroll
    for (int j = 0; j < 4; ++j) {
        int col  = colbase + j * 16 + coll;  // 0..511 within group
        float bv = bias[g * BOUT + col];
        size_t ocol = (size_t)g * BOUT + col;
#pragma unroll
        for (int i = 0; i < 4; ++i) {
            int rbase = m0 + wm * 64 + i * 16 + rowq;
#pragma unroll
            for (int r = 0; r < 4; ++r)
                out[(size_t)(rbase + r) * NCOL + ocol] = acc[i][j][r] + bv;
        }
    }
}

extern "C" void kernel_launch(void* const* d_in, const int* in_sizes, int n_in,
                              void* d_out, int out_size, void* d_ws, size_t ws_size,
                              hipStream_t stream) {
    const float* x    = (const float*)d_in[0];
    const float* W    = (const float*)d_in[1];
    const float* bias = (const float*)d_in[2];
    float* out  = (float*)d_out;
    __bf16* wsB = (__bf16*)d_ws;  // 4 MB of scratch for bf16-swizzled W

    // W -> bf16 fragment-major swizzle (runs every call; ws is re-poisoned)
    convW_kernel<<<1024, 256, 0, stream>>>(W, wsB);
    // 8 groups x 128 m-tiles x 4 n-tiles = 4096 blocks
    bgemm_kernel<<<4096, 256, 0, stream>>>(x, wsB, bias, out);
}